// Round 8
// baseline (389.494 us; speedup 1.0000x reference)
//
#include <hip/hip_runtime.h>
#include <hip/hip_bf16.h>
#include <cstdint>

typedef _Float16 f16;
typedef f16 f16x8 __attribute__((ext_vector_type(8)));
typedef float f32x4 __attribute__((ext_vector_type(4)));

static constexpr int Hh = 64;   // hidden
static constexpr int Tt = 30;   // seq len
static constexpr int Ii = 9;    // input features
static constexpr int BT = 64;   // batch tile per block
static constexpr int HP = 72;   // h-row stride (halves): 144 B rows -> A-frags 16B-aligned (b128)
static constexpr int XP = 24;   // x-row stride (halves): 48 B rows, 16B-aligned
static constexpr int CS = 68;   // c1 LDS stride (floats): <=2-way bank aliasing (free)

static constexpr float L2E = 1.4426950408889634f;

__device__ __forceinline__ float bf2f(unsigned short u){
  return __uint_as_float(((unsigned int)u) << 16);
}

template<bool BF16>
__device__ __forceinline__ float ldv(const void* p, long i){
  if constexpr (BF16) return bf2f(((const unsigned short*)p)[i]);
  else                return ((const float*)p)[i];
}

// Gates arrive pre-scaled by log2e (i,f,o) and 2*log2e (g); cell state kept as
// chat = -2*log2e*c  (so exp2(chat) = e^{-2c}).
// R7 (verified -3.5%): merged reciprocal for i*tanh(g).
// R9 (verified -0.8%): f-gate reciprocal merged into the same divide ->
// 5 exp2 + 2 rcp:
//   chat' = [chat*P + s*(1+Ff)] / ((1+Ff)*P),  P=(1+G)(1+Fi)   [one rcp]
//   o*tanh(c) = (1-E)/((1+E)(1+Fo))                            [one rcp]
// Overflow audit: |gate_raw|<=~19 -> denom <= 2^112 < 2^127; num <= 2^90.
__device__ __forceinline__ float cell_update(float ai, float af, float ag, float ao, float& chat){
  float Fi = __builtin_amdgcn_exp2f(-ai);
  float Ff = __builtin_amdgcn_exp2f(-af);
  float G  = __builtin_amdgcn_exp2f(-ag);
  float P  = (1.0f + G) * (1.0f + Fi);
  float Bf = 1.0f + Ff;
  float s  = __builtin_fmaf(G, 2.0f*L2E, -2.0f*L2E);           // = -2L2E*(1-G)
  float num = __builtin_fmaf(chat, P, s * Bf);                 // chat*P + s*(1+Ff)
  chat = num * __builtin_amdgcn_rcpf(Bf * P);
  float E  = __builtin_amdgcn_exp2f(chat);
  float Fo = __builtin_amdgcn_exp2f(-ao);
  float rot = __builtin_amdgcn_rcpf((1.0f + E) * (1.0f + Fo)); // 1/((1+E)(1+Fo))
  return (1.0f - E) * rot;                                     // h = o*tanh(c)
}

// bf16 data reinterpreted as fp32 shows huge/NaN exponents
__global__ void detect_dtype(const void* x, int* flag){
  if (threadIdx.x == 0 && blockIdx.x == 0){
    const float* f = (const float*)x;
    int big = 0;
    for (int i = 0; i < 64; ++i){
      float v = f[i];
      if (!(fabsf(v) < 1e10f)) big = 1;
    }
    *flag = big;
  }
}

// MFMA 16x16x32 f16 mapping:
//   A: m = lane&15, k = (lane>>4)*8 + j
//   B: n = lane&15, k = (lane>>4)*8 + j  (= row n of W[256][K], contiguous k)
//   C/D: n = lane&15, m = (lane>>4)*4 + reg
// Wave specialization: waves 0-3 = layer0 step s; waves 4-7 = layer1 step s-1.
// Barrier skeleton IDENTICAL in both branches (R5-proven): 31 barriers, same
// order. R10 (verified ~neutral): s-loop unrolled x2, compile-time parity.
// R11: s_setprio(1) around each mt-tile's MFMA cluster (T5). Waves are
// role-diverse (2x L0 + 2x L1 per SIMD, different instruction streams,
// intra-step slippage allowed) — boosting the MFMA-entering wave lets its
// matrix ops issue between other waves' trans bursts.
// R6 post-mortem: +16 net live regs SPILLS (WRITE_SIZE +8MB, -8%).
// R8 post-mortem: c1 LDS->regs (+4 net regs in layer1) still LOST 4% — AGPR
// shuffling (v_accvgpr_*) on the contended VALU port. Layer-1 has ZERO
// register headroom; LDS-pipe ops are cheap, VALU-issue ops are expensive.
template<bool BF16>
__device__ void lstm_body(const void* __restrict__ x,
                          const void* __restrict__ Wih0, const void* __restrict__ Whh0,
                          const void* __restrict__ bih0, const void* __restrict__ bhh0,
                          const void* __restrict__ Wih1, const void* __restrict__ Whh1,
                          const void* __restrict__ bih1, const void* __restrict__ bhh1,
                          const void* __restrict__ gmma, const void* __restrict__ beta,
                          void* __restrict__ out,
                          f16* h0s, f16* h1s, f16* xs, float* c1l)
{
  const int tid  = threadIdx.x;
  const int w8   = tid >> 6;
  const int lane = tid & 63;
  const int c    = lane & 15;
  const int q    = lane >> 4;
  const int lay  = w8 >> 2;
  const int w    = w8 & 3;
  const long base = (long)blockIdx.x * BT;
  const float gsc[4] = { L2E, L2E, 2.0f*L2E, L2E };   // per-gate exp2 pre-scale

  // ---- zero-init: h0/h1 buf0, xs both bufs (incl pads), c1 state ----
  for (int i = tid; i < BT*HP; i += 512){ h0s[i] = (f16)0.f; h1s[i] = (f16)0.f; }
  for (int i = tid; i < 2*BT*XP; i += 512) xs[i] = (f16)0.f;
  for (int i = tid; i < BT*CS;   i += 512) c1l[i] = 0.f;
  __syncthreads();

  // ---- stage x[t=0] ----
  if (lay == 0){
    for (int e = tid; e < BT*Ii; e += 256){
      int s = e / 9, i = e - s*9;
      xs[s*XP + i] = (f16)ldv<BF16>(x, (base + s)*(long)(Tt*Ii) + i);
    }
  }
  __syncthreads();

  if (lay == 0){
    // ================= LAYER 0 waves =================
    f16x8 W0[4][2];  f16x8 Wx[4];  f32x4 bsp[4];
    for (int g = 0; g < 4; ++g){
      const int n = 64*g + 16*w + c;
      const float sc = gsc[g];
      for (int kt = 0; kt < 2; ++kt){
        const long off = (long)n*64 + kt*32 + q*8;
        for (int j = 0; j < 8; ++j) W0[g][kt][j] = (f16)(sc * ldv<BF16>(Whh0, off + j));
      }
      f16x8 bi = {};
      if (q == 0){ for (int j = 0; j < 8; ++j) bi[j] = (f16)(sc * ldv<BF16>(Wih0, (long)n*9 + j)); }
      else if (q == 1){ bi[0] = (f16)(sc * ldv<BF16>(Wih0, (long)n*9 + 8)); }
      Wx[g] = bi;
      float bb = sc * (ldv<BF16>(bih0, n) + ldv<BF16>(bhh0, n));
      bsp[g] = (f32x4){ bb, bb, bb, bb };
    }
    // x staging bookkeeping (hoisted /9)
    int xs_off[3]; int xg[3]; bool xv[3];
    for (int it = 0; it < 3; ++it){
      int e = tid + 256*it;
      xv[it] = (e < BT*Ii);
      int s = e / 9, i = e - s*9;
      if (!xv[it]){ s = 0; i = 0; }
      xs_off[it] = s*XP + i;
      xg[it] = s*(Tt*Ii) + Ii + i;
    }
    const void* xb = BF16 ? (const void*)((const unsigned short*)x + base*(Tt*Ii))
                          : (const void*)((const float*)x + base*(Tt*Ii));
    float c0[4][4] = {};   // chat-domain cell state
    float xpv[3];
    const int aoff = c*HP + q*8;
    const int xoff = c*XP + q*8;
    const int woff = 4*q*HP + 16*w + c;

    // One timestep; rb/pf are compile-time at every call site.
    auto stepL0 = [&](int rb, bool pf){
      const int wb = rb ^ 1;
      const f16* ha = h0s + rb*(BT*HP) + aoff;
      const f16* xa = xs  + rb*(BT*XP) + xoff;
      f16*       hw = h0s + wb*(BT*HP) + woff;
      f16*       xw = xs  + wb*(BT*XP);
      if (pf){
#pragma unroll
        for (int it = 0; it < 3; ++it){
          if (xv[it]) xpv[it] = ldv<BF16>(xb, xg[it]);
          xg[it] += Ii;
        }
      }
#pragma unroll
      for (int mt = 0; mt < 4; ++mt){
        f16x8 ah0 = *(const f16x8*)(ha + mt*16*HP);        // ds_read_b128
        f16x8 ah1 = *(const f16x8*)(ha + mt*16*HP + 32);
        f16x8 ax = {};
        if (q < 2) ax = *(const f16x8*)(xa + mt*16*XP);
        f32x4 acc[4];
        __builtin_amdgcn_s_setprio(1);
#pragma unroll
        for (int g = 0; g < 4; ++g){
          f32x4 a = __builtin_amdgcn_mfma_f32_16x16x32_f16(ah0, W0[g][0], bsp[g], 0,0,0);
          a = __builtin_amdgcn_mfma_f32_16x16x32_f16(ah1, W0[g][1], a, 0,0,0);
          a = __builtin_amdgcn_mfma_f32_16x16x32_f16(ax,  Wx[g],    a, 0,0,0);
          acc[g] = a;
        }
        __builtin_amdgcn_s_setprio(0);
#pragma unroll
        for (int r = 0; r < 4; ++r){
          float h = cell_update(acc[0][r], acc[1][r], acc[2][r], acc[3][r], c0[mt][r]);
          hw[(mt*16 + r)*HP] = (f16)h;
        }
      }
      if (pf){
#pragma unroll
        for (int it = 0; it < 3; ++it)
          if (xv[it]) xw[xs_off[it]] = (f16)xpv[it];
      }
    };

    stepL0(0, true);  __syncthreads();     // s=0
    stepL0(1, true);  __syncthreads();     // s=1
#pragma clang loop unroll(disable)
    for (int it13 = 0; it13 < 13; ++it13){ // s=2..27
      stepL0(0, true); __syncthreads();
      stepL0(1, true); __syncthreads();
    }
    stepL0(0, true);  __syncthreads();     // s=28
    stepL0(1, false); __syncthreads();     // s=29 (no prefetch)
    __syncthreads();                       // s=30 (L0 idle)
  } else {
    // ================= LAYER 1 waves =================
    f16x8 W1a[4][2], W1b[4][2];  f32x4 bsp[4];
    for (int g = 0; g < 4; ++g){
      const int n = 64*g + 16*w + c;
      const float sc = gsc[g];
      for (int kt = 0; kt < 2; ++kt){
        const long off = (long)n*64 + kt*32 + q*8;
        for (int j = 0; j < 8; ++j){
          W1a[g][kt][j] = (f16)(sc * ldv<BF16>(Wih1, off + j));
          W1b[g][kt][j] = (f16)(sc * ldv<BF16>(Whh1, off + j));
        }
      }
      float bb = sc * (ldv<BF16>(bih1, n) + ldv<BF16>(bhh1, n));
      bsp[g] = (f32x4){ bb, bb, bb, bb };
    }
    const int aoff = c*HP + q*8;
    const int woff = 4*q*HP + 16*w + c;
    float* cb = c1l + 4*q*CS + 16*w + c;

    // One timestep for layer1 (computes h1[s-1]); p compile-time at call site.
    auto stepL1 = [&](int p){
      const f16* a0 = h0s + p*(BT*HP) + aoff;        // h0[s-1]
      const f16* a1 = h1s + (p ^ 1)*(BT*HP) + aoff;  // h1[s-2]
      f16*       hw = h1s + p*(BT*HP) + woff;        // h1[s-1]
#pragma unroll
      for (int mt = 0; mt < 4; ++mt){
        f16x8 a00 = *(const f16x8*)(a0 + mt*16*HP);
        f16x8 a01 = *(const f16x8*)(a0 + mt*16*HP + 32);
        f16x8 a10 = *(const f16x8*)(a1 + mt*16*HP);
        f16x8 a11 = *(const f16x8*)(a1 + mt*16*HP + 32);
        f32x4 acc[4];
        __builtin_amdgcn_s_setprio(1);
#pragma unroll
        for (int g = 0; g < 4; ++g){
          f32x4 a = __builtin_amdgcn_mfma_f32_16x16x32_f16(a00, W1a[g][0], bsp[g], 0,0,0);
          a = __builtin_amdgcn_mfma_f32_16x16x32_f16(a01, W1a[g][1], a, 0,0,0);
          a = __builtin_amdgcn_mfma_f32_16x16x32_f16(a10, W1b[g][0], a, 0,0,0);
          a = __builtin_amdgcn_mfma_f32_16x16x32_f16(a11, W1b[g][1], a, 0,0,0);
          acc[g] = a;
        }
        __builtin_amdgcn_s_setprio(0);
#pragma unroll
        for (int r = 0; r < 4; ++r){
          float ch = cb[(mt*16 + r)*CS];
          float h = cell_update(acc[0][r], acc[1][r], acc[2][r], acc[3][r], ch);
          cb[(mt*16 + r)*CS] = ch;
          hw[(mt*16 + r)*HP] = (f16)h;
        }
      }
    };

    __syncthreads();                       // s=0 (L1 idle)
    stepL1(1); __syncthreads();            // s=1
#pragma clang loop unroll(disable)
    for (int it13 = 0; it13 < 13; ++it13){ // s=2..27
      stepL1(0); __syncthreads();
      stepL1(1); __syncthreads();
    }
    stepL1(0); __syncthreads();            // s=28
    stepL1(1); __syncthreads();            // s=29
    stepL1(0); __syncthreads();            // s=30
  }

  // ---- LayerNorm over final h1 (h1s buf (Tt&1)=0, f16). xs dead -> scratch. ----
  const f16* hf = h1s;
  float* mus = (float*)xs;
  float* rss = mus + BT;
  if (tid < BT){
    float sm = 0.f, s2 = 0.f;
    for (int u = 0; u < Hh; ++u){ float v = (float)hf[tid*HP + u]; sm += v; s2 += v*v; }
    float m   = sm * (1.0f/Hh);
    float var = s2 * (1.0f/Hh) - m*m;   // biased var, matches jnp.var
    mus[tid] = m;
    rss[tid] = rsqrtf(var + 1e-5f);
  }
  __syncthreads();
  for (int it = 0; it < (BT*Hh)/512; ++it){
    int idx = it*512 + tid;
    int sIdx = idx >> 6, u = idx & 63;
    float v = ((float)hf[sIdx*HP + u] - mus[sIdx]) * rss[sIdx];
    v = __builtin_fmaf(v, ldv<BF16>(gmma, u), ldv<BF16>(beta, u));
    long o = base*Hh + idx;
    if constexpr (BF16) ((__hip_bfloat16*)out)[o] = __float2bfloat16(v);
    else                ((float*)out)[o] = v;
  }
}

// (512,4): VGPR cap 128 -> 4 waves/SIMD, 2 blocks/CU (LDS ~59 KB).
__global__ __launch_bounds__(512, 4) void lstm_fused(
    const void* __restrict__ x,
    const void* __restrict__ Wih0, const void* __restrict__ Whh0,
    const void* __restrict__ bih0, const void* __restrict__ bhh0,
    const void* __restrict__ Wih1, const void* __restrict__ Whh1,
    const void* __restrict__ bih1, const void* __restrict__ bhh1,
    const void* __restrict__ gmma, const void* __restrict__ beta,
    void* __restrict__ out, const int* __restrict__ flag)
{
  __shared__ __align__(16) f16 h0s[2*BT*HP];    // 18432 B
  __shared__ __align__(16) f16 h1s[2*BT*HP];    // 18432 B
  __shared__ __align__(16) f16 xs[2*BT*XP];     //  6144 B (LN scratch after loop)
  __shared__ __align__(16) float c1l[BT*CS];    // 17408 B  -> total 60416 B
  if (*flag)
    lstm_body<true >(x, Wih0, Whh0, bih0, bhh0, Wih1, Whh1, bih1, bhh1, gmma, beta,
                     out, h0s, h1s, xs, c1l);
  else
    lstm_body<false>(x, Wih0, Whh0, bih0, bhh0, Wih1, Whh1, bih1, bhh1, gmma, beta,
                     out, h0s, h1s, xs, c1l);
}

extern "C" void kernel_launch(void* const* d_in, const int* in_sizes, int n_in,
                              void* d_out, int out_size, void* d_ws, size_t ws_size,
                              hipStream_t stream) {
  const int B = in_sizes[0] / (Tt * Ii);   // 65536
  int* flag = (int*)d_ws;
  hipLaunchKernelGGL(detect_dtype, dim3(1), dim3(64), 0, stream, d_in[0], flag);
  hipLaunchKernelGGL(lstm_fused, dim3(B / BT), dim3(512), 0, stream,
                     d_in[0], d_in[1], d_in[2], d_in[3], d_in[4], d_in[5], d_in[6],
                     d_in[7], d_in[8], d_in[9], d_in[10], d_out, (const int*)flag);
}

// Round 9
// 384.808 us; speedup vs baseline: 1.0122x; 1.0122x over previous
//
#include <hip/hip_runtime.h>
#include <hip/hip_bf16.h>
#include <cstdint>

typedef _Float16 f16;
typedef f16 f16x8 __attribute__((ext_vector_type(8)));
typedef float f32x4 __attribute__((ext_vector_type(4)));

static constexpr int Hh = 64;   // hidden
static constexpr int Tt = 30;   // seq len
static constexpr int Ii = 9;    // input features
static constexpr int BT = 64;   // batch tile per block
static constexpr int HP = 72;   // h-row stride (halves): 144 B rows -> A-frags 16B-aligned (b128)
static constexpr int XP = 24;   // x-row stride (halves): 48 B rows, 16B-aligned
static constexpr int CS = 68;   // c1 LDS stride (floats): <=2-way bank aliasing (free)

static constexpr float L2E = 1.4426950408889634f;

__device__ __forceinline__ float bf2f(unsigned short u){
  return __uint_as_float(((unsigned int)u) << 16);
}

template<bool BF16>
__device__ __forceinline__ float ldv(const void* p, long i){
  if constexpr (BF16) return bf2f(((const unsigned short*)p)[i]);
  else                return ((const float*)p)[i];
}

// Gates arrive pre-scaled by log2e (i,f,o) and 2*log2e (g); cell state kept as
// chat = -2*log2e*c  (so exp2(chat) = e^{-2c}).
// R7 (verified -3.5%): merged reciprocal for i*tanh(g).
// R9 (verified -0.8%): f-gate reciprocal merged into the same divide ->
// 5 exp2 + 2 rcp:
//   chat' = [chat*P + s*(1+Ff)] / ((1+Ff)*P),  P=(1+G)(1+Fi)   [one rcp]
//   o*tanh(c) = (1-E)/((1+E)(1+Fo))                            [one rcp]
// Overflow audit: |gate_raw|<=~19 -> denom <= 2^112 < 2^127; num <= 2^90.
__device__ __forceinline__ float cell_update(float ai, float af, float ag, float ao, float& chat){
  float Fi = __builtin_amdgcn_exp2f(-ai);
  float Ff = __builtin_amdgcn_exp2f(-af);
  float G  = __builtin_amdgcn_exp2f(-ag);
  float P  = (1.0f + G) * (1.0f + Fi);
  float Bf = 1.0f + Ff;
  float s  = __builtin_fmaf(G, 2.0f*L2E, -2.0f*L2E);           // = -2L2E*(1-G)
  float num = __builtin_fmaf(chat, P, s * Bf);                 // chat*P + s*(1+Ff)
  chat = num * __builtin_amdgcn_rcpf(Bf * P);
  float E  = __builtin_amdgcn_exp2f(chat);
  float Fo = __builtin_amdgcn_exp2f(-ao);
  float rot = __builtin_amdgcn_rcpf((1.0f + E) * (1.0f + Fo)); // 1/((1+E)(1+Fo))
  return (1.0f - E) * rot;                                     // h = o*tanh(c)
}

// bf16 data reinterpreted as fp32 shows huge/NaN exponents
__global__ void detect_dtype(const void* x, int* flag){
  if (threadIdx.x == 0 && blockIdx.x == 0){
    const float* f = (const float*)x;
    int big = 0;
    for (int i = 0; i < 64; ++i){
      float v = f[i];
      if (!(fabsf(v) < 1e10f)) big = 1;
    }
    *flag = big;
  }
}

// MFMA 16x16x32 f16 mapping:
//   A: m = lane&15, k = (lane>>4)*8 + j
//   B: n = lane&15, k = (lane>>4)*8 + j  (= row n of W[256][K], contiguous k)
//   C/D: n = lane&15, m = (lane>>4)*4 + reg
// Wave specialization: waves 0-3 = layer0 step s; waves 4-7 = layer1 step s-1.
// Barrier skeleton IDENTICAL in both branches (R5-proven): 31 barriers, same
// order. R10 (verified best, 334 us): s-loop unrolled x2, compile-time parity.
// R11 post-mortem (REVERTED): s_setprio pairs around MFMA clusters act as
// scheduling fences -> live ranges extend -> scratch spill (WRITE +11MB,
// -3.3%). Third confirmation with R6/R8: ANY transform that extends live
// ranges in this kernel spills; the 128-unified-reg budget has zero slack.
// R6 post-mortem: +16 net live regs SPILLS (WRITE_SIZE +8MB, -8%).
// R8 post-mortem: c1 LDS->regs (+4 net regs in layer1) still LOST 4% — AGPR
// shuffling (v_accvgpr_*) on the contended VALU port. Layer-1 has ZERO
// register headroom; LDS-pipe ops are cheap, VALU-issue ops are expensive.
template<bool BF16>
__device__ void lstm_body(const void* __restrict__ x,
                          const void* __restrict__ Wih0, const void* __restrict__ Whh0,
                          const void* __restrict__ bih0, const void* __restrict__ bhh0,
                          const void* __restrict__ Wih1, const void* __restrict__ Whh1,
                          const void* __restrict__ bih1, const void* __restrict__ bhh1,
                          const void* __restrict__ gmma, const void* __restrict__ beta,
                          void* __restrict__ out,
                          f16* h0s, f16* h1s, f16* xs, float* c1l)
{
  const int tid  = threadIdx.x;
  const int w8   = tid >> 6;
  const int lane = tid & 63;
  const int c    = lane & 15;
  const int q    = lane >> 4;
  const int lay  = w8 >> 2;
  const int w    = w8 & 3;
  const long base = (long)blockIdx.x * BT;
  const float gsc[4] = { L2E, L2E, 2.0f*L2E, L2E };   // per-gate exp2 pre-scale

  // ---- zero-init: h0/h1 buf0, xs both bufs (incl pads), c1 state ----
  for (int i = tid; i < BT*HP; i += 512){ h0s[i] = (f16)0.f; h1s[i] = (f16)0.f; }
  for (int i = tid; i < 2*BT*XP; i += 512) xs[i] = (f16)0.f;
  for (int i = tid; i < BT*CS;   i += 512) c1l[i] = 0.f;
  __syncthreads();

  // ---- stage x[t=0] ----
  if (lay == 0){
    for (int e = tid; e < BT*Ii; e += 256){
      int s = e / 9, i = e - s*9;
      xs[s*XP + i] = (f16)ldv<BF16>(x, (base + s)*(long)(Tt*Ii) + i);
    }
  }
  __syncthreads();

  if (lay == 0){
    // ================= LAYER 0 waves =================
    f16x8 W0[4][2];  f16x8 Wx[4];  f32x4 bsp[4];
    for (int g = 0; g < 4; ++g){
      const int n = 64*g + 16*w + c;
      const float sc = gsc[g];
      for (int kt = 0; kt < 2; ++kt){
        const long off = (long)n*64 + kt*32 + q*8;
        for (int j = 0; j < 8; ++j) W0[g][kt][j] = (f16)(sc * ldv<BF16>(Whh0, off + j));
      }
      f16x8 bi = {};
      if (q == 0){ for (int j = 0; j < 8; ++j) bi[j] = (f16)(sc * ldv<BF16>(Wih0, (long)n*9 + j)); }
      else if (q == 1){ bi[0] = (f16)(sc * ldv<BF16>(Wih0, (long)n*9 + 8)); }
      Wx[g] = bi;
      float bb = sc * (ldv<BF16>(bih0, n) + ldv<BF16>(bhh0, n));
      bsp[g] = (f32x4){ bb, bb, bb, bb };
    }
    // x staging bookkeeping (hoisted /9)
    int xs_off[3]; int xg[3]; bool xv[3];
    for (int it = 0; it < 3; ++it){
      int e = tid + 256*it;
      xv[it] = (e < BT*Ii);
      int s = e / 9, i = e - s*9;
      if (!xv[it]){ s = 0; i = 0; }
      xs_off[it] = s*XP + i;
      xg[it] = s*(Tt*Ii) + Ii + i;
    }
    const void* xb = BF16 ? (const void*)((const unsigned short*)x + base*(Tt*Ii))
                          : (const void*)((const float*)x + base*(Tt*Ii));
    float c0[4][4] = {};   // chat-domain cell state
    float xpv[3];
    const int aoff = c*HP + q*8;
    const int xoff = c*XP + q*8;
    const int woff = 4*q*HP + 16*w + c;

    // One timestep; rb/pf are compile-time at every call site.
    auto stepL0 = [&](int rb, bool pf){
      const int wb = rb ^ 1;
      const f16* ha = h0s + rb*(BT*HP) + aoff;
      const f16* xa = xs  + rb*(BT*XP) + xoff;
      f16*       hw = h0s + wb*(BT*HP) + woff;
      f16*       xw = xs  + wb*(BT*XP);
      if (pf){
#pragma unroll
        for (int it = 0; it < 3; ++it){
          if (xv[it]) xpv[it] = ldv<BF16>(xb, xg[it]);
          xg[it] += Ii;
        }
      }
#pragma unroll
      for (int mt = 0; mt < 4; ++mt){
        f16x8 ah0 = *(const f16x8*)(ha + mt*16*HP);        // ds_read_b128
        f16x8 ah1 = *(const f16x8*)(ha + mt*16*HP + 32);
        f16x8 ax = {};
        if (q < 2) ax = *(const f16x8*)(xa + mt*16*XP);
        f32x4 acc[4];
#pragma unroll
        for (int g = 0; g < 4; ++g){
          f32x4 a = __builtin_amdgcn_mfma_f32_16x16x32_f16(ah0, W0[g][0], bsp[g], 0,0,0);
          a = __builtin_amdgcn_mfma_f32_16x16x32_f16(ah1, W0[g][1], a, 0,0,0);
          a = __builtin_amdgcn_mfma_f32_16x16x32_f16(ax,  Wx[g],    a, 0,0,0);
          acc[g] = a;
        }
#pragma unroll
        for (int r = 0; r < 4; ++r){
          float h = cell_update(acc[0][r], acc[1][r], acc[2][r], acc[3][r], c0[mt][r]);
          hw[(mt*16 + r)*HP] = (f16)h;
        }
      }
      if (pf){
#pragma unroll
        for (int it = 0; it < 3; ++it)
          if (xv[it]) xw[xs_off[it]] = (f16)xpv[it];
      }
    };

    stepL0(0, true);  __syncthreads();     // s=0
    stepL0(1, true);  __syncthreads();     // s=1
#pragma clang loop unroll(disable)
    for (int it13 = 0; it13 < 13; ++it13){ // s=2..27
      stepL0(0, true); __syncthreads();
      stepL0(1, true); __syncthreads();
    }
    stepL0(0, true);  __syncthreads();     // s=28
    stepL0(1, false); __syncthreads();     // s=29 (no prefetch)
    __syncthreads();                       // s=30 (L0 idle)
  } else {
    // ================= LAYER 1 waves =================
    f16x8 W1a[4][2], W1b[4][2];  f32x4 bsp[4];
    for (int g = 0; g < 4; ++g){
      const int n = 64*g + 16*w + c;
      const float sc = gsc[g];
      for (int kt = 0; kt < 2; ++kt){
        const long off = (long)n*64 + kt*32 + q*8;
        for (int j = 0; j < 8; ++j){
          W1a[g][kt][j] = (f16)(sc * ldv<BF16>(Wih1, off + j));
          W1b[g][kt][j] = (f16)(sc * ldv<BF16>(Whh1, off + j));
        }
      }
      float bb = sc * (ldv<BF16>(bih1, n) + ldv<BF16>(bhh1, n));
      bsp[g] = (f32x4){ bb, bb, bb, bb };
    }
    const int aoff = c*HP + q*8;
    const int woff = 4*q*HP + 16*w + c;
    float* cb = c1l + 4*q*CS + 16*w + c;

    // One timestep for layer1 (computes h1[s-1]); p compile-time at call site.
    auto stepL1 = [&](int p){
      const f16* a0 = h0s + p*(BT*HP) + aoff;        // h0[s-1]
      const f16* a1 = h1s + (p ^ 1)*(BT*HP) + aoff;  // h1[s-2]
      f16*       hw = h1s + p*(BT*HP) + woff;        // h1[s-1]
#pragma unroll
      for (int mt = 0; mt < 4; ++mt){
        f16x8 a00 = *(const f16x8*)(a0 + mt*16*HP);
        f16x8 a01 = *(const f16x8*)(a0 + mt*16*HP + 32);
        f16x8 a10 = *(const f16x8*)(a1 + mt*16*HP);
        f16x8 a11 = *(const f16x8*)(a1 + mt*16*HP + 32);
        f32x4 acc[4];
#pragma unroll
        for (int g = 0; g < 4; ++g){
          f32x4 a = __builtin_amdgcn_mfma_f32_16x16x32_f16(a00, W1a[g][0], bsp[g], 0,0,0);
          a = __builtin_amdgcn_mfma_f32_16x16x32_f16(a01, W1a[g][1], a, 0,0,0);
          a = __builtin_amdgcn_mfma_f32_16x16x32_f16(a10, W1b[g][0], a, 0,0,0);
          a = __builtin_amdgcn_mfma_f32_16x16x32_f16(a11, W1b[g][1], a, 0,0,0);
          acc[g] = a;
        }
#pragma unroll
        for (int r = 0; r < 4; ++r){
          float ch = cb[(mt*16 + r)*CS];
          float h = cell_update(acc[0][r], acc[1][r], acc[2][r], acc[3][r], ch);
          cb[(mt*16 + r)*CS] = ch;
          hw[(mt*16 + r)*HP] = (f16)h;
        }
      }
    };

    __syncthreads();                       // s=0 (L1 idle)
    stepL1(1); __syncthreads();            // s=1
#pragma clang loop unroll(disable)
    for (int it13 = 0; it13 < 13; ++it13){ // s=2..27
      stepL1(0); __syncthreads();
      stepL1(1); __syncthreads();
    }
    stepL1(0); __syncthreads();            // s=28
    stepL1(1); __syncthreads();            // s=29
    stepL1(0); __syncthreads();            // s=30
  }

  // ---- LayerNorm over final h1 (h1s buf (Tt&1)=0, f16). xs dead -> scratch. ----
  const f16* hf = h1s;
  float* mus = (float*)xs;
  float* rss = mus + BT;
  if (tid < BT){
    float sm = 0.f, s2 = 0.f;
    for (int u = 0; u < Hh; ++u){ float v = (float)hf[tid*HP + u]; sm += v; s2 += v*v; }
    float m   = sm * (1.0f/Hh);
    float var = s2 * (1.0f/Hh) - m*m;   // biased var, matches jnp.var
    mus[tid] = m;
    rss[tid] = rsqrtf(var + 1e-5f);
  }
  __syncthreads();
  for (int it = 0; it < (BT*Hh)/512; ++it){
    int idx = it*512 + tid;
    int sIdx = idx >> 6, u = idx & 63;
    float v = ((float)hf[sIdx*HP + u] - mus[sIdx]) * rss[sIdx];
    v = __builtin_fmaf(v, ldv<BF16>(gmma, u), ldv<BF16>(beta, u));
    long o = base*Hh + idx;
    if constexpr (BF16) ((__hip_bfloat16*)out)[o] = __float2bfloat16(v);
    else                ((float*)out)[o] = v;
  }
}

// (512,4): VGPR cap 128 -> 4 waves/SIMD, 2 blocks/CU (LDS ~59 KB).
__global__ __launch_bounds__(512, 4) void lstm_fused(
    const void* __restrict__ x,
    const void* __restrict__ Wih0, const void* __restrict__ Whh0,
    const void* __restrict__ bih0, const void* __restrict__ bhh0,
    const void* __restrict__ Wih1, const void* __restrict__ Whh1,
    const void* __restrict__ bih1, const void* __restrict__ bhh1,
    const void* __restrict__ gmma, const void* __restrict__ beta,
    void* __restrict__ out, const int* __restrict__ flag)
{
  __shared__ __align__(16) f16 h0s[2*BT*HP];    // 18432 B
  __shared__ __align__(16) f16 h1s[2*BT*HP];    // 18432 B
  __shared__ __align__(16) f16 xs[2*BT*XP];     //  6144 B (LN scratch after loop)
  __shared__ __align__(16) float c1l[BT*CS];    // 17408 B  -> total 60416 B
  if (*flag)
    lstm_body<true >(x, Wih0, Whh0, bih0, bhh0, Wih1, Whh1, bih1, bhh1, gmma, beta,
                     out, h0s, h1s, xs, c1l);
  else
    lstm_body<false>(x, Wih0, Whh0, bih0, bhh0, Wih1, Whh1, bih1, bhh1, gmma, beta,
                     out, h0s, h1s, xs, c1l);
}

extern "C" void kernel_launch(void* const* d_in, const int* in_sizes, int n_in,
                              void* d_out, int out_size, void* d_ws, size_t ws_size,
                              hipStream_t stream) {
  const int B = in_sizes[0] / (Tt * Ii);   // 65536
  int* flag = (int*)d_ws;
  hipLaunchKernelGGL(detect_dtype, dim3(1), dim3(64), 0, stream, d_in[0], flag);
  hipLaunchKernelGGL(lstm_fused, dim3(B / BT), dim3(512), 0, stream,
                     d_in[0], d_in[1], d_in[2], d_in[3], d_in[4], d_in[5], d_in[6],
                     d_in[7], d_in[8], d_in[9], d_in[10], d_out, (const int*)flag);
}